// Round 16
// baseline (5166.039 us; speedup 1.0000x reference)
//
#include <hip/hip_runtime.h>
#include <stddef.h>

typedef unsigned int u32;
typedef __attribute__((ext_vector_type(8))) short short8;
typedef __attribute__((ext_vector_type(4))) float f32x4;

#define TC 32                      // timestep chunk
#define NCH 16                     // number of chunks
#define XWF ((size_t)TC * 2048 * 32)   // floats per xW buffer (8,388,608 B)
#define H0F ((size_t)TC * 32 * 512)    // floats per h0 slot   (2,097,152 B)

__device__ __forceinline__ float sigmoidf_(float x) {
    return 1.0f / (1.0f + __expf(-x));
}
__device__ __forceinline__ float tanhf_(float x) {
    float ax = fabsf(x);
    float e = __expf(-2.0f * ax);
    float t = (1.0f - e) / (1.0f + e);
    return copysignf(t, x);
}
__device__ __forceinline__ u32 cvtpk(float lo, float hi) {
    u32 r;
    asm("v_cvt_pk_bf16_f32 %0, %1, %2" : "=v"(r) : "v"(lo), "v"(hi));
    return r;
}
__device__ __forceinline__ void stg_cv1(float* p, float v) {
    asm volatile("global_store_dword %0, %1, off sc0 sc1" :: "v"(p), "v"(v) : "memory");
}
__device__ __forceinline__ void stg_cv2(float* p, float2 v) {
    asm volatile("global_store_dwordx2 %0, %1, off sc0 sc1" :: "v"(p), "v"(v) : "memory");
}
__device__ __forceinline__ void stg_cu32(u32* p, u32 v) {
    asm volatile("global_store_dword %0, %1, off sc0 sc1" :: "v"(p), "v"(v) : "memory");
}
__device__ __forceinline__ u32 ldg_cu32(const u32* p) {
    u32 v;
    asm volatile("global_load_dword %0, %1, off sc0 sc1\n\t"
                 "s_waitcnt vmcnt(0)" : "=v"(v) : "v"(p) : "memory");
    return v;
}
__device__ __forceinline__ float4 ldg_cv4(const float* p) {
    float4 v;
    asm volatile("global_load_dwordx4 %0, %1, off sc0 sc1\n\t"
                 "s_waitcnt vmcnt(0)" : "=v"(v) : "v"(p) : "memory");
    return v;
}
// tagged poll: 16 (h,tag) pairs; on success packs 16 h -> 2x int4 of bf16
__device__ __forceinline__ bool pollph(const float* p, u32 tt, int4& A, int4& B) {
    float4 q0, q1, q2, q3, q4, q5, q6, q7;
    asm volatile(
        "global_load_dwordx4 %0, %8, off sc0 sc1\n\t"
        "global_load_dwordx4 %1, %8, off offset:16 sc0 sc1\n\t"
        "global_load_dwordx4 %2, %8, off offset:32 sc0 sc1\n\t"
        "global_load_dwordx4 %3, %8, off offset:48 sc0 sc1\n\t"
        "global_load_dwordx4 %4, %8, off offset:64 sc0 sc1\n\t"
        "global_load_dwordx4 %5, %8, off offset:80 sc0 sc1\n\t"
        "global_load_dwordx4 %6, %8, off offset:96 sc0 sc1\n\t"
        "global_load_dwordx4 %7, %8, off offset:112 sc0 sc1\n\t"
        "s_waitcnt vmcnt(0)"
        : "=&v"(q0), "=&v"(q1), "=&v"(q2), "=&v"(q3),
          "=&v"(q4), "=&v"(q5), "=&v"(q6), "=&v"(q7)
        : "v"(p) : "memory");
    const bool ok =
        (__float_as_uint(q0.y) == tt) & (__float_as_uint(q0.w) == tt) &
        (__float_as_uint(q1.y) == tt) & (__float_as_uint(q1.w) == tt) &
        (__float_as_uint(q2.y) == tt) & (__float_as_uint(q2.w) == tt) &
        (__float_as_uint(q3.y) == tt) & (__float_as_uint(q3.w) == tt) &
        (__float_as_uint(q4.y) == tt) & (__float_as_uint(q4.w) == tt) &
        (__float_as_uint(q5.y) == tt) & (__float_as_uint(q5.w) == tt) &
        (__float_as_uint(q6.y) == tt) & (__float_as_uint(q6.w) == tt) &
        (__float_as_uint(q7.y) == tt) & (__float_as_uint(q7.w) == tt);
    A.x = (int)cvtpk(q0.x, q0.z); A.y = (int)cvtpk(q1.x, q1.z);
    A.z = (int)cvtpk(q2.x, q2.z); A.w = (int)cvtpk(q3.x, q3.z);
    B.x = (int)cvtpk(q4.x, q4.z); B.y = (int)cvtpk(q5.x, q5.z);
    B.z = (int)cvtpk(q6.x, q6.z); B.w = (int)cvtpk(q7.x, q7.z);
    return ok;
}

// ============================================================================
// beat: ONE dispatch per pipeline beat k.
//   blocks 0..63   : rec  (bid<32: r0(k) layer0; bid>=32: r1(k-1) layer1) --
//                    R15's verified MFMA engine + tagged ring (1 RT/step).
//   blocks 64..319 : proj (p<128: g0(k+1) from inp; p>=128: g1(k) from h0
//                    slot being written by r0(k) NOW -- polls r0's prog).
//   Rec blocks have the lowest IDs -> scheduled first -> resident. g1 waits
//   only on r0, which never waits on this beat's proj -> no deadlock.
// ============================================================================
__global__ void __launch_bounds__(512, 1)
beat(const float* __restrict__ inp,
     const float* __restrict__ Whh0, const float* __restrict__ Wih0,
     const float* __restrict__ bih0, const float* __restrict__ bhh0,
     const float* __restrict__ Whh1, const float* __restrict__ Wih1,
     const float* __restrict__ bih1, const float* __restrict__ bhh1,
     float* __restrict__ out,
     float* __restrict__ xW0b, float* __restrict__ xW1b, float* __restrict__ h0b,
     float* __restrict__ cst0, float* __restrict__ cst1,
     float* __restrict__ ring0, float* __restrict__ ring1,
     u32* __restrict__ prog0, int k)
{
    __shared__ int4 smem_[2128];                 // 34,048 B shared pool
    const int bid = blockIdx.x;
    const int tid = threadIdx.x;

    if (bid < 64) {
        // ==================== rec role (R15 engine + tagged ring) ====================
        const int half = bid >> 5;
        const int lb = bid & 31;
        int t0;
        const float *Whh, *xW;
        float *ring, *cst;
        if (half == 0) {
            if (k < 0 || k > 15) return;
            t0 = k * TC; Whh = Whh0; xW = xW0b + (size_t)(k & 1) * XWF;
            ring = ring0; cst = cst0;
        } else {
            if (k < 1) return;
            const int c = k - 1;
            t0 = c * TC; Whh = Whh1; xW = xW1b + (size_t)(c & 1) * XWF;
            ring = ring1; cst = cst1;
        }
        int4* xh4 = smem_;                       // [32][64] bf16 h, 32 KB

        const int hb = lb << 4;
        const int w = tid >> 6, l = tid & 63;
        const int ct = w >> 2, h4 = w & 3;
        const int q = l >> 4, cl = l & 15;

        // A-fragments: W_hh gate-interleaved rows, bf16, resident
        const int g_a = cl & 3, hp_a = cl >> 2;
        const int jw = (g_a << 9) + hb + (h4 << 2) + hp_a;
        short8 af[16];
#pragma unroll
        for (int c = 0; c < 16; ++c) {
            const float* wp = Whh + (size_t)jw * 512 + c * 32 + q * 8;
            const float4 v0 = *(const float4*)wp;
            const float4 v1 = *(const float4*)(wp + 4);
            union { short8 s; u32 wd[4]; } u;
            u.wd[0] = cvtpk(v0.x, v0.y); u.wd[1] = cvtpk(v0.z, v0.w);
            u.wd[2] = cvtpk(v1.x, v1.y); u.wd[3] = cvtpk(v1.z, v1.w);
            af[c] = u.s;
        }
        const int hh = hb + (h4 << 2) + q;       // global hidden (this lane's cell)
        const int b  = (ct << 4) + cl;           // global batch
        float c_reg = cst[(size_t)b * 512 + hh];
        const int sn = tid >> 4;                 // staging batch
        const int sk = (tid & 15) << 5;          // staging k-offset
        const int sb4 = (tid & 15) << 2;
        u32* prog_self = prog0 + lb * 16;

        for (int tl = 0; tl < TC; ++tl) {
            const int t = t0 + tl;
            if (t > 0) {
                const float* rp = ring + ((size_t)((t - 1) & 3) * 16384 +
                                          (size_t)sn * 512 + sk) * 2;
                int4 pk0, pk1, pk2, pk3;
                while (!pollph(rp,      (u32)t, pk0, pk1)) {}
                while (!pollph(rp + 32, (u32)t, pk2, pk3)) {}
                xh4[sn * 64 + ((sb4 + 0) ^ (sn & 7))] = pk0;
                xh4[sn * 64 + ((sb4 + 1) ^ (sn & 7))] = pk1;
                xh4[sn * 64 + ((sb4 + 2) ^ (sn & 7))] = pk2;
                xh4[sn * 64 + ((sb4 + 3) ^ (sn & 7))] = pk3;
            }
            __syncthreads();

            const float* xwb = xW + ((size_t)tl * 2048 + hh) * 32 + b;
            f32x4 acc;
            acc[0] = xwb[0];
            acc[1] = xwb[512 * 32];
            acc[2] = xwb[1024 * 32];
            acc[3] = xwb[1536 * 32];
            if (t > 0) {
#pragma unroll
                for (int c = 0; c < 16; ++c) {
                    const int sp = ((c << 2) + q) ^ (b & 7);
                    const short8 bf = *reinterpret_cast<const short8*>(&xh4[b * 64 + sp]);
                    acc = __builtin_amdgcn_mfma_f32_16x16x32_bf16(af[c], bf, acc, 0, 0, 0);
                }
            }
            const float i_ = sigmoidf_(acc[0]);
            const float f_ = sigmoidf_(acc[1]);
            const float g_ = tanhf_(acc[2]);
            const float o_ = sigmoidf_(acc[3]);
            c_reg = f_ * c_reg + i_ * g_;
            const float hv = o_ * tanhf_(c_reg);
            if (half == 0) {
                // h0 slot: coherent (g1 reads it in THIS dispatch)
                stg_cv1(h0b + (size_t)(k & 1) * H0F +
                        (size_t)tl * 16384 + (size_t)b * 512 + hh, hv);
            } else {
                out[((size_t)b * 512 + t) * 512 + hh] = hv;   // plain (post-launch)
            }
            float2 pr; pr.x = hv; pr.y = __uint_as_float((u32)(t + 1));
            stg_cv2(ring + ((size_t)(t & 3) * 16384 + (size_t)b * 512 + hh) * 2, pr);
            asm volatile("s_waitcnt vmcnt(0)" ::: "memory");
            __syncthreads();
            if (half == 0 && tid == 0) stg_cu32(prog_self, (u32)(t + 1));
        }
        cst[(size_t)b * 512 + hh] = c_reg;
        return;
    }

    // ==================== proj role (512-thread 128x128 tile GEMM) ====================
    const int p = bid - 64;
    const int halfp = p >> 7;
    const int mbase = ((p & 127) >> 3) * 128;
    const int nt = p & 7;
    const float *W, *bih, *bhh, *X;
    float* xW;
    size_t sXb, sXt;
    int tb;
    bool cohw = false;
    if (halfp == 0) {                            // g0(k+1): x from inp
        if (k > 14) return;
        const int kc = k + 1;
        W = Wih0; bih = bih0; bhh = bhh0; X = inp;
        sXb = (size_t)512 * 512; sXt = 512; tb = kc * TC;
        xW = xW0b + (size_t)(kc & 1) * XWF;
    } else {                                     // g1(k): x from h0 slot (live)
        if (k < 0 || k > 15) return;
        W = Wih1; bih = bih1; bhh = bhh1; X = h0b + (size_t)(k & 1) * H0F;
        sXb = 512; sXt = 16384; tb = 0;
        xW = xW1b + (size_t)(k & 1) * XWF; cohw = true;
        if (tid < 32) {                          // wait for r0(k) to pass our t-range
            const u32 thr = (u32)(k * TC + nt * 4 + 4);
            u32 v;
            do { v = ldg_cu32(prog0 + tid * 16); } while (v < thr);
        }
        __syncthreads();
    }

    float (*As)[132] = (float (*)[132])smem_;
    float (*Bs)[132] = (float (*)[132])((char*)smem_ + 32 * 132 * 4);
    const int tm = tid >> 5;                     // 16 -> 8 m's
    const int tn = tid & 31;                     // 32 -> 4 n's
    float acc[8][4] = {};

    for (int kc2 = 0; kc2 < 512; kc2 += 32) {
        __syncthreads();
#pragma unroll
        for (int u = 0; u < 2; ++u) {
            const int f = u * 512 + tid;
            const int m = f >> 3, k4 = f & 7;
            const float4 v = *(const float4*)(W + (size_t)(mbase + m) * 512 + kc2 + k4 * 4);
            As[k4 * 4 + 0][m] = v.x; As[k4 * 4 + 1][m] = v.y;
            As[k4 * 4 + 2][m] = v.z; As[k4 * 4 + 3][m] = v.w;
        }
#pragma unroll
        for (int u = 0; u < 2; ++u) {
            const int f = u * 512 + tid;
            const int n = f >> 3, k4 = f & 7;
            const int tl = n >> 5, b2 = n & 31;
            const float* src = X + (size_t)b2 * sXb + (size_t)(tb + nt * 4 + tl) * sXt
                               + kc2 + k4 * 4;
            const float4 v = cohw ? ldg_cv4(src) : *(const float4*)src;
            Bs[k4 * 4 + 0][n] = v.x; Bs[k4 * 4 + 1][n] = v.y;
            Bs[k4 * 4 + 2][n] = v.z; Bs[k4 * 4 + 3][n] = v.w;
        }
        __syncthreads();
#pragma unroll 8
        for (int kk = 0; kk < 32; ++kk) {
            const float4 a0 = *(const float4*)&As[kk][tm * 8];
            const float4 a1 = *(const float4*)&As[kk][tm * 8 + 4];
            const float4 b0 = *(const float4*)&Bs[kk][tn * 4];
            const float am[8] = {a0.x, a0.y, a0.z, a0.w, a1.x, a1.y, a1.z, a1.w};
            const float bn[4] = {b0.x, b0.y, b0.z, b0.w};
#pragma unroll
            for (int i = 0; i < 8; ++i)
#pragma unroll
                for (int j = 0; j < 4; ++j)
                    acc[i][j] = fmaf(am[i], bn[j], acc[i][j]);
        }
    }
    const int tl_loc = nt * 4 + (tn >> 3);
    const int bcol = (tn & 7) * 4;
#pragma unroll
    for (int i = 0; i < 8; ++i) {
        const int m = mbase + tm * 8 + i;
        const float bias = bih[m] + bhh[m];
        float4 v = {acc[i][0] + bias, acc[i][1] + bias, acc[i][2] + bias, acc[i][3] + bias};
        *(float4*)(xW + ((size_t)tl_loc * 2048 + m) * 32 + bcol) = v;
    }
}

// ============================================================================
extern "C" void kernel_launch(void* const* d_in, const int* in_sizes, int n_in,
                              void* d_out, int out_size, void* d_ws, size_t ws_size,
                              hipStream_t stream) {
    const float* inp  = (const float*)d_in[0];
    const float* Wih0 = (const float*)d_in[1];
    const float* Whh0 = (const float*)d_in[2];
    const float* bih0 = (const float*)d_in[3];
    const float* bhh0 = (const float*)d_in[4];
    const float* Wih1 = (const float*)d_in[5];
    const float* Whh1 = (const float*)d_in[6];
    const float* bih1 = (const float*)d_in[7];
    const float* bhh1 = (const float*)d_in[8];
    float* out = (float*)d_out;

    char* ws = (char*)d_ws;
    float* xW0b  = (float*)ws;                          // 2 x 8,388,608 B
    float* xW1b  = (float*)(ws + 16777216);             // 2 x 8,388,608 B
    float* h0b   = (float*)(ws + 33554432);             // 2 x 2,097,152 B
    float* cst0  = (float*)(ws + 37748736);             // 65,536 B
    float* cst1  = (float*)(ws + 37814272);             // 65,536 B
    float* ring0 = (float*)(ws + 37879808);             // 524,288 B (float2 pairs)
    float* ring1 = (float*)(ws + 38404096);             // 524,288 B
    u32*   prog0 = (u32*) (ws + 38928384);              // 2,048 B
    // zero c-state + rings (tag epoch) + prog each launch -> replay-safe
    (void)hipMemsetAsync(ws + 37748736, 0, 131072 + 2 * 524288 + 4096, stream);

    // beat k: rec { r0(k), r1(k-1) } || proj { g0(k+1), g1(k) }
    for (int k = -1; k <= NCH; ++k) {
        hipLaunchKernelGGL(beat, dim3(320), dim3(512), 0, stream,
                           inp, Whh0, Wih0, bih0, bhh0,
                           Whh1, Wih1, bih1, bhh1, out,
                           xW0b, xW1b, h0b, cst0, cst1, ring0, ring1, prog0, k);
    }
}